// Round 9
// baseline (75.303 us; speedup 1.0000x reference)
//
#include <hip/hip_runtime.h>
#include <cstdint>
#include <cstddef>

#define NN 16384
#define FF 128
#define CAPD 96    // max slots per dst; in-degree ~1+Poisson(31); P(>96) ~ 1e-15

typedef float f32x4 __attribute__((ext_vector_type(4)));
typedef short short8 __attribute__((ext_vector_type(8)));

__device__ __forceinline__ unsigned short f2bf(float f) {
    unsigned u = __float_as_uint(f);
    u += 0x7fffu + ((u >> 16) & 1u);   // round-to-nearest-even
    return (unsigned short)(u >> 16);
}

__device__ __forceinline__ short8 ld8(const unsigned short* p) {
    return *(const short8*)p;
}

__device__ __forceinline__ float blo(unsigned v) { return __uint_as_float(v << 16); }
__device__ __forceinline__ float bhi(unsigned v) { return __uint_as_float(v & 0xffff0000u); }

// ---------------------------------------------------------------------------
// Kernel 1: convert x,W,B to bf16 AND zero the cnt array (one launch, no deps)
// blocks 0..2047: x. 2048..2063: W. 2064..2079: B. 2080..2143: cnt=0.
// ---------------------------------------------------------------------------
__global__ __launch_bounds__(256) void k_prep(const float4* __restrict__ x,
                                              const float4* __restrict__ W,
                                              const float4* __restrict__ B,
                                              ushort4* __restrict__ xb,
                                              ushort4* __restrict__ Wb,
                                              ushort4* __restrict__ Bb,
                                              int* __restrict__ cnt) {
    int bid = blockIdx.x;
    if (bid >= 2080) {   // zero cnt: 64 blocks x 256 = 16384 ints
        cnt[(bid - 2080) * 256 + threadIdx.x] = 0;
        return;
    }
    const float4* src; ushort4* dst; int i;
    if (bid < 2048)      { src = x; dst = xb; i = bid * 256 + threadIdx.x; }
    else if (bid < 2064) { src = W; dst = Wb; i = (bid - 2048) * 256 + threadIdx.x; }
    else                 { src = B; dst = Bb; i = (bid - 2064) * 256 + threadIdx.x; }
    float4 v = src[i];
    ushort4 o;
    o.x = f2bf(v.x); o.y = f2bf(v.y); o.z = f2bf(v.z); o.w = f2bf(v.w);
    dst[i] = o;
}

// ---------------------------------------------------------------------------
// Kernel 2: bucket-CSR fill, 4 edges/thread, u16 payload.
// ---------------------------------------------------------------------------
__global__ __launch_bounds__(256) void k_fill(const int* __restrict__ ei,
                                              int* __restrict__ cnt,
                                              unsigned short* __restrict__ slots,
                                              int E) {
    int t = blockIdx.x * 256 + threadIdx.x;          // E/4 threads
    const int4 s4 = ((const int4*)ei)[t];            // row 0: sources
    const int4 d4 = ((const int4*)(ei + E))[t];      // row 1: dests
    int sl0 = atomicAdd(&cnt[d4.x], 1);
    int sl1 = atomicAdd(&cnt[d4.y], 1);
    int sl2 = atomicAdd(&cnt[d4.z], 1);
    int sl3 = atomicAdd(&cnt[d4.w], 1);
    if (sl0 < CAPD) slots[(size_t)d4.x * CAPD + sl0] = (unsigned short)s4.x;
    if (sl1 < CAPD) slots[(size_t)d4.y * CAPD + sl1] = (unsigned short)s4.y;
    if (sl2 < CAPD) slots[(size_t)d4.z * CAPD + sl2] = (unsigned short)s4.z;
    if (sl3 < CAPD) slots[(size_t)d4.w * CAPD + sl3] = (unsigned short)s4.w;
}

// ---------------------------------------------------------------------------
// Kernel 3 (fused agg+gemm): one block per 32-row output tile.
// Phase A: 4 waves x 8 dst-rows, ballot-dedup + gather (as before), result
//   bf16-rounded into LDS agg tile (stride 68 u32: <=2-way bank aliasing).
// Phase B: out[rows][0:128] = agg @ W^T + x @ B^T via mfma_f32_16x16x32_bf16;
//   A-frags for the agg term read from LDS, everything else from global.
// ---------------------------------------------------------------------------
__global__ __launch_bounds__(256) void k_aggemm(const int* __restrict__ cnt,
                                                const unsigned short* __restrict__ slots,
                                                const unsigned* __restrict__ xb,
                                                const unsigned short* __restrict__ Wb,
                                                const unsigned short* __restrict__ Bb,
                                                float* __restrict__ out) {
    __shared__ unsigned bm[4][512];       // per-wave 16384-bit dedup bitmap
    __shared__ int sl_lds[4][CAPD];       // per-wave slot cache
    __shared__ unsigned agg[32 * 68];     // 32 rows x 64 u32 (2 bf16 each), padded
    const int w = threadIdx.x >> 6;
    const int l = threadIdx.x & 63;
    const int tile = blockIdx.x;          // 512 tiles x 32 rows

    // ---- phase A ----
    for (int r = 0; r < 8; ++r) {
        const int i = tile * 32 + w * 8 + r;
#pragma unroll
        for (int j = 0; j < 8; ++j) bm[w][l + 64 * j] = 0u;
        int n = cnt[i]; if (n > CAPD) n = CAPD;
        const unsigned short* sl = slots + (size_t)i * CAPD;

        unsigned long long k0 = 0, k1 = 0;
#pragma unroll
        for (int h = 0; h < 2; ++h) {
            int j = l + 64 * h;
            bool keep = false;
            if (j < n) {
                int s = sl[j];
                sl_lds[w][j] = s;
                unsigned bit = 1u << (s & 31);
                unsigned old = atomicOr(&bm[w][s >> 5], bit);
                keep = !(old & bit);      // exactly one winner per distinct src
            }
            unsigned long long m = __ballot(keep);
            if (h == 0) k0 = m; else k1 = m;
        }
        const int deg = __popcll(k0) + __popcll(k1);

        const unsigned* xbl = xb + l;
        float a0 = 0.f, a1 = 0.f;
        int j = 0;
        for (; j + 8 <= n; j += 8) {
            int s[8]; unsigned v[8];
#pragma unroll
            for (int q = 0; q < 8; ++q) s[q] = sl_lds[w][j + q];   // LDS broadcast
#pragma unroll
            for (int q = 0; q < 8; ++q) v[q] = xbl[(size_t)s[q] * 64];
            unsigned bits8 = (unsigned)((j < 64 ? k0 : k1) >> (j & 63)) & 255u;
            if (bits8 == 255u) {          // no duplicates in batch (~99%)
                a0 += blo(v[0]) + blo(v[1]) + blo(v[2]) + blo(v[3])
                    + blo(v[4]) + blo(v[5]) + blo(v[6]) + blo(v[7]);
                a1 += bhi(v[0]) + bhi(v[1]) + bhi(v[2]) + bhi(v[3])
                    + bhi(v[4]) + bhi(v[5]) + bhi(v[6]) + bhi(v[7]);
            } else {                      // wave-uniform rare path
#pragma unroll
                for (int q = 0; q < 8; ++q) {
                    float fl = (float)((bits8 >> q) & 1u);
                    a0 += fl * blo(v[q]);
                    a1 += fl * bhi(v[q]);
                }
            }
        }
        for (; j < n; ++j) {
            int s = sl_lds[w][j];
            unsigned long long mm = (j < 64) ? k0 : k1;
            float fl = (float)((mm >> (j & 63)) & 1ull);
            unsigned v = xbl[(size_t)s * 64];
            a0 += fl * blo(v);
            a1 += fl * bhi(v);
        }
        float inv = 1.f / (float)deg;
        agg[(w * 8 + r) * 68 + l] = ((unsigned)f2bf(a1 * inv) << 16) | f2bf(a0 * inv);
    }
    __syncthreads();

    // ---- phase B ----
    const int row0g = tile * 32 + (w >> 1) * 16;   // global row base
    const int row0l = (w >> 1) * 16;               // LDS row base
    const int col0 = (w & 1) * 64;
    const int lr = l & 15;
    const int lq = l >> 4;                         // quarter-wave index 0..3
    const unsigned short* xbs = (const unsigned short*)xb;

    f32x4 acc[4];
#pragma unroll
    for (int f = 0; f < 4; ++f) acc[f] = (f32x4)0.f;

#pragma unroll
    for (int ks = 0; ks < 4; ++ks) {               // agg @ W^T  (K=128)
        short8 a = *(const short8*)&agg[(row0l + lr) * 68 + ks * 16 + lq * 4];
#pragma unroll
        for (int f = 0; f < 4; ++f) {
            short8 b = ld8(&Wb[(size_t)(col0 + f * 16 + lr) * FF + ks * 32 + lq * 8]);
            acc[f] = __builtin_amdgcn_mfma_f32_16x16x32_bf16(a, b, acc[f], 0, 0, 0);
        }
    }
#pragma unroll
    for (int ks = 0; ks < 4; ++ks) {               // x @ B^T  (K=128)
        short8 a = ld8(&xbs[(size_t)(row0g + lr) * FF + ks * 32 + lq * 8]);
#pragma unroll
        for (int f = 0; f < 4; ++f) {
            short8 b = ld8(&Bb[(size_t)(col0 + f * 16 + lr) * FF + ks * 32 + lq * 8]);
            acc[f] = __builtin_amdgcn_mfma_f32_16x16x32_bf16(a, b, acc[f], 0, 0, 0);
        }
    }
#pragma unroll
    for (int f = 0; f < 4; ++f)
#pragma unroll
        for (int r4 = 0; r4 < 4; ++r4)
            out[(size_t)(row0g + lq * 4 + r4) * FF + col0 + f * 16 + lr] = acc[f][r4];
}

// ---------------------------------------------------------------------------
extern "C" void kernel_launch(void* const* d_in, const int* in_sizes, int n_in,
                              void* d_out, int out_size, void* d_ws, size_t ws_size,
                              hipStream_t stream) {
    const float* x = (const float*)d_in[0];
    const int* ei = (const int*)d_in[1];
    const float* W = (const float*)d_in[2];
    const float* B = (const float*)d_in[3];
    float* out = (float*)d_out;
    const int E = in_sizes[1] / 2;

    unsigned char* ws = (unsigned char*)d_ws;
    int* cnt = (int*)ws;                                       // 64 KB
    unsigned short* slots = (unsigned short*)(ws + 65536);     // 3 MB (u16)
    unsigned* xb = (unsigned*)(ws + 3211264);                  // 4 MB bf16 x
    unsigned short* Wb = (unsigned short*)(ws + 7405568);      // 32 KB
    unsigned short* Bb = (unsigned short*)(ws + 7438336);      // 32 KB

    k_prep<<<2144, 256, 0, stream>>>((const float4*)x, (const float4*)W,
                                     (const float4*)B, (ushort4*)xb,
                                     (ushort4*)Wb, (ushort4*)Bb, cnt);
    k_fill<<<E / 4 / 256, 256, 0, stream>>>(ei, cnt, slots, E);
    k_aggemm<<<NN / 32, 256, 0, stream>>>(cnt, slots, xb, Wb, Bb, out);
}

// Round 11
// 61.930 us; speedup vs baseline: 1.2159x; 1.2159x over previous
//
#include <hip/hip_runtime.h>
#include <cstdint>
#include <cstddef>

#define NN 16384
#define FF 128
#define CAPD 96    // max slots per dst; in-degree ~1+Poisson(31); P(>96) ~ 1e-15

typedef float f32x4 __attribute__((ext_vector_type(4)));
typedef short short8 __attribute__((ext_vector_type(8)));

__device__ __forceinline__ unsigned short f2bf(float f) {
    unsigned u = __float_as_uint(f);
    u += 0x7fffu + ((u >> 16) & 1u);   // round-to-nearest-even
    return (unsigned short)(u >> 16);
}

__device__ __forceinline__ short8 ld8(const unsigned short* p) {
    return *(const short8*)p;
}

__device__ __forceinline__ float blo(unsigned v) { return __uint_as_float(v << 16); }
__device__ __forceinline__ float bhi(unsigned v) { return __uint_as_float(v & 0xffff0000u); }

// ---------------------------------------------------------------------------
// Kernel 1: convert x,W,B to bf16 AND zero the cnt array (one launch, no deps)
// blocks 0..2047: x. 2048..2063: W. 2064..2079: B. 2080..2143: cnt=0.
// ---------------------------------------------------------------------------
__global__ __launch_bounds__(256) void k_prep(const float4* __restrict__ x,
                                              const float4* __restrict__ W,
                                              const float4* __restrict__ B,
                                              ushort4* __restrict__ xb,
                                              ushort4* __restrict__ Wb,
                                              ushort4* __restrict__ Bb,
                                              int* __restrict__ cnt) {
    int bid = blockIdx.x;
    if (bid >= 2080) {   // zero cnt: 64 blocks x 256 = 16384 ints
        cnt[(bid - 2080) * 256 + threadIdx.x] = 0;
        return;
    }
    const float4* src; ushort4* dst; int i;
    if (bid < 2048)      { src = x; dst = xb; i = bid * 256 + threadIdx.x; }
    else if (bid < 2064) { src = W; dst = Wb; i = (bid - 2048) * 256 + threadIdx.x; }
    else                 { src = B; dst = Bb; i = (bid - 2064) * 256 + threadIdx.x; }
    float4 v = src[i];
    ushort4 o;
    o.x = f2bf(v.x); o.y = f2bf(v.y); o.z = f2bf(v.z); o.w = f2bf(v.w);
    dst[i] = o;
}

// ---------------------------------------------------------------------------
// Kernel 2: bucket-CSR fill, 4 edges/thread with int4 loads of both edge rows
// and 4 independent atomicAdd->store chains in flight.
// ---------------------------------------------------------------------------
__global__ __launch_bounds__(256) void k_fill(const int* __restrict__ ei,
                                              int* __restrict__ cnt,
                                              unsigned short* __restrict__ slots,
                                              int E) {
    int t = blockIdx.x * 256 + threadIdx.x;          // E/4 threads
    const int4 s4 = ((const int4*)ei)[t];            // row 0: sources
    const int4 d4 = ((const int4*)(ei + E))[t];      // row 1: dests
    int sl0 = atomicAdd(&cnt[d4.x], 1);
    int sl1 = atomicAdd(&cnt[d4.y], 1);
    int sl2 = atomicAdd(&cnt[d4.z], 1);
    int sl3 = atomicAdd(&cnt[d4.w], 1);
    if (sl0 < CAPD) slots[(size_t)d4.x * CAPD + sl0] = (unsigned short)s4.x;
    if (sl1 < CAPD) slots[(size_t)d4.y * CAPD + sl1] = (unsigned short)s4.y;
    if (sl2 < CAPD) slots[(size_t)d4.z * CAPD + sl2] = (unsigned short)s4.z;
    if (sl3 < CAPD) slots[(size_t)d4.w * CAPD + sl3] = (unsigned short)s4.w;
}

// ---------------------------------------------------------------------------
// Kernel 3: per-dst aggregation, ballot-dedup.
// One wave per dst; lane l owns features 2l,2l+1. Duplicates ~0.1% of edges:
// mark first-occurrence per slot via per-wave LDS bitmap atomicOr, build a
// 96-bit keep mask with __ballot (wave-uniform regs), gather ALL n slots,
// masked-add only in batches containing a duplicate. deg = popcount(mask).
// All LDS per-wave -> no __syncthreads.
// ---------------------------------------------------------------------------
__global__ __launch_bounds__(256) void k_agg(const int* __restrict__ cnt,
                                             const unsigned short* __restrict__ slots,
                                             const unsigned* __restrict__ xb,
                                             unsigned* __restrict__ aggs) {
    __shared__ unsigned bm[4][512];     // 16384-bit node bitmap per wave
    __shared__ int sl_lds[4][CAPD];     // slot cache for broadcast reads
    const int w = threadIdx.x >> 6;
    const int l = threadIdx.x & 63;
    const int i = blockIdx.x * 4 + w;
#pragma unroll
    for (int j = 0; j < 8; ++j) bm[w][l + 64 * j] = 0u;
    int n = cnt[i]; if (n > CAPD) n = CAPD;
    const unsigned short* sl = slots + (size_t)i * CAPD;

    unsigned long long k0, k1;
#pragma unroll
    for (int h = 0; h < 2; ++h) {
        int j = l + 64 * h;
        bool keep = false;
        if (j < n) {
            int s = sl[j];
            sl_lds[w][j] = s;
            unsigned bit = 1u << (s & 31);
            unsigned old = atomicOr(&bm[w][s >> 5], bit);
            keep = !(old & bit);          // exactly one winner per distinct src
        }
        unsigned long long m = __ballot(keep);
        if (h == 0) k0 = m; else k1 = m;
    }
    const int deg = __popcll(k0) + __popcll(k1);

    const unsigned* xbl = xb + l;
    float a0 = 0.f, a1 = 0.f;
    int j = 0;
    for (; j + 8 <= n; j += 8) {
        int s[8]; unsigned v[8];
#pragma unroll
        for (int q = 0; q < 8; ++q) s[q] = sl_lds[w][j + q];   // LDS broadcast
#pragma unroll
        for (int q = 0; q < 8; ++q) v[q] = xbl[(size_t)s[q] * 64];
        unsigned bits8 = (unsigned)((j < 64 ? k0 : k1) >> (j & 63)) & 255u;
        if (bits8 == 255u) {              // no duplicates in batch (~99%)
            a0 += blo(v[0]) + blo(v[1]) + blo(v[2]) + blo(v[3])
                + blo(v[4]) + blo(v[5]) + blo(v[6]) + blo(v[7]);
            a1 += bhi(v[0]) + bhi(v[1]) + bhi(v[2]) + bhi(v[3])
                + bhi(v[4]) + bhi(v[5]) + bhi(v[6]) + bhi(v[7]);
        } else {                          // wave-uniform rare path
#pragma unroll
            for (int q = 0; q < 8; ++q) {
                float fl = (float)((bits8 >> q) & 1u);
                a0 += fl * blo(v[q]);
                a1 += fl * bhi(v[q]);
            }
        }
    }
    for (; j < n; ++j) {
        int s = sl_lds[w][j];
        unsigned long long mm = (j < 64) ? k0 : k1;
        float fl = (float)((mm >> (j & 63)) & 1ull);
        unsigned v = xbl[(size_t)s * 64];
        a0 += fl * blo(v);
        a1 += fl * bhi(v);
    }
    float inv = 1.f / (float)deg;
    unsigned o = ((unsigned)f2bf(a1 * inv) << 16) | f2bf(a0 * inv);
    aggs[(size_t)i * 64 + l] = o;
}

// ---------------------------------------------------------------------------
// Kernel 4: out = aggs @ W^T + x @ B^T via mfma_f32_16x16x32_bf16.
// 512 blocks = 256 m-blocks x 2 n-halves; 4 waves, each 16 rows x 64 cols.
// Direct-global fragment loads; W/B L2-resident, act rows L2/L3-hot.
// ---------------------------------------------------------------------------
__global__ __launch_bounds__(256) void k_gemm(const unsigned short* __restrict__ aggs,
                                              const unsigned short* __restrict__ xb,
                                              const unsigned short* __restrict__ Wb,
                                              const unsigned short* __restrict__ Bb,
                                              float* __restrict__ out) {
    const int bid = blockIdx.x;
    const int mb = bid >> 1, nb = bid & 1;
    const int w = threadIdx.x >> 6, l = threadIdx.x & 63;
    const int row0 = mb * 64 + w * 16;
    const int col0 = nb * 64;
    const int lr = l & 15;
    const int lk = (l >> 4) * 8;

    f32x4 acc[4];
#pragma unroll
    for (int f = 0; f < 4; ++f) acc[f] = (f32x4)0.f;

#pragma unroll
    for (int p = 0; p < 2; ++p) {
        const unsigned short* A  = p ? xb : aggs;
        const unsigned short* Wt = p ? Bb : Wb;
#pragma unroll
        for (int ks = 0; ks < 4; ++ks) {
            const int k = ks * 32 + lk;
            short8 a = ld8(&A[(size_t)(row0 + lr) * FF + k]);
#pragma unroll
            for (int f = 0; f < 4; ++f) {
                short8 b = ld8(&Wt[(size_t)(col0 + f * 16 + lr) * FF + k]);
                acc[f] = __builtin_amdgcn_mfma_f32_16x16x32_bf16(a, b, acc[f], 0, 0, 0);
            }
        }
    }
#pragma unroll
    for (int f = 0; f < 4; ++f)
#pragma unroll
        for (int r = 0; r < 4; ++r)
            out[(size_t)(row0 + (l >> 4) * 4 + r) * FF + col0 + f * 16 + lr] = acc[f][r];
}

// ---------------------------------------------------------------------------
extern "C" void kernel_launch(void* const* d_in, const int* in_sizes, int n_in,
                              void* d_out, int out_size, void* d_ws, size_t ws_size,
                              hipStream_t stream) {
    const float* x = (const float*)d_in[0];
    const int* ei = (const int*)d_in[1];
    const float* W = (const float*)d_in[2];
    const float* B = (const float*)d_in[3];
    float* out = (float*)d_out;
    const int E = in_sizes[1] / 2;

    unsigned char* ws = (unsigned char*)d_ws;
    int* cnt = (int*)ws;                                       // 64 KB
    unsigned short* slots = (unsigned short*)(ws + 65536);     // 3 MB (u16)
    unsigned* xb = (unsigned*)(ws + 3211264);                  // 4 MB bf16 x
    unsigned* aggs = (unsigned*)(ws + 7405568);                // 4 MB bf16 agg
    unsigned short* Wb = (unsigned short*)(ws + 11599872);     // 32 KB
    unsigned short* Bb = (unsigned short*)(ws + 11632640);     // 32 KB

    k_prep<<<2144, 256, 0, stream>>>((const float4*)x, (const float4*)W,
                                     (const float4*)B, (ushort4*)xb,
                                     (ushort4*)Wb, (ushort4*)Bb, cnt);
    k_fill<<<E / 4 / 256, 256, 0, stream>>>(ei, cnt, slots, E);
    k_agg<<<NN / 4, 256, 0, stream>>>(cnt, slots, xb, aggs);
    k_gemm<<<512, 256, 0, stream>>>((const unsigned short*)aggs,
                                    (const unsigned short*)xb, Wb, Bb, out);
}